// Round 1
// baseline (1915.088 us; speedup 1.0000x reference)
//
#include <hip/hip_runtime.h>
#include <math.h>

#define N_NODES 131072
#define N_EDGES 2097152
#define DIM     64
#define BSUB    4096
#define NREL    3
#define NBASES  2

// ---------------- CSR build ----------------

__global__ void zero_kernel(int* __restrict__ p, int n) {
    int i = blockIdx.x * 256 + threadIdx.x;
    if (i < n) p[i] = 0;
}

__global__ void hist_kernel(const int* __restrict__ dst, int* __restrict__ cnt) {
    int e = blockIdx.x * 256 + threadIdx.x;
    if (e < N_EDGES) atomicAdd(&cnt[dst[e]], 1);
}

// block-level exclusive scan of 256 counts; block total -> bsum
__global__ void scan1_kernel(const int* __restrict__ cnt, int* __restrict__ scanned,
                             int* __restrict__ bsum) {
    __shared__ int s[256];
    int tid = threadIdx.x;
    int i = blockIdx.x * 256 + tid;
    int v = cnt[i];
    s[tid] = v;
    __syncthreads();
    int val = v;
    for (int off = 1; off < 256; off <<= 1) {
        int tmp = (tid >= off) ? s[tid - off] : 0;
        __syncthreads();
        val += tmp;
        s[tid] = val;
        __syncthreads();
    }
    scanned[i] = val - v;                 // exclusive
    if (tid == 255) bsum[blockIdx.x] = val;  // inclusive total
}

// exclusive scan of the 512 block sums, in place
__global__ void scan2_kernel(int* __restrict__ bsum) {
    __shared__ int s[512];
    int tid = threadIdx.x;
    int v = bsum[tid];
    s[tid] = v;
    __syncthreads();
    int val = v;
    for (int off = 1; off < 512; off <<= 1) {
        int tmp = (tid >= off) ? s[tid - off] : 0;
        __syncthreads();
        val += tmp;
        s[tid] = val;
        __syncthreads();
    }
    bsum[tid] = val - v;
}

__global__ void scan3_kernel(int* __restrict__ offs, const int* __restrict__ bsum,
                             int* __restrict__ cursor) {
    int i = blockIdx.x * 256 + threadIdx.x;
    int v = offs[i] + bsum[blockIdx.x];
    offs[i] = v;
    cursor[i] = v;
    if (i == 0) offs[N_NODES] = N_EDGES;
}

// scatter edges into CSR order; pack src (17b) | etype<<20
__global__ void fill_kernel(const int* __restrict__ src, const int* __restrict__ dst,
                            const int* __restrict__ et, const float* __restrict__ m1,
                            const float* __restrict__ m2, int* __restrict__ cursor,
                            int* __restrict__ csr_se, float* __restrict__ cm1,
                            float* __restrict__ cm2) {
    int e = blockIdx.x * 256 + threadIdx.x;
    if (e >= N_EDGES) return;
    int d = dst[e];
    int p = atomicAdd(&cursor[d], 1);
    csr_se[p] = src[e] | (et[e] << 20);
    cm1[p] = m1[e];
    cm2[p] = m2[e];
}

// ---------------- weight stacking ----------------
// wstk[conv][256][64]: rows 0..191 = W_r (basis-combined, r=0..2), rows 192..255 = W_self
__global__ void wstk_kernel(const float* __restrict__ lV, const float* __restrict__ lC,
                            const float* __restrict__ lW, const float* __restrict__ gV,
                            const float* __restrict__ gC, const float* __restrict__ gW,
                            float* __restrict__ wstk) {
    int idx = blockIdx.x * 256 + threadIdx.x;   // 6*256*64 total
    if (idx >= 6 * 256 * 64) return;
    int o = idx & 63;
    int r = (idx >> 6) & 255;
    int c = idx >> 14;            // conv 0..5
    int layer = c >> 1;
    bool isglobal = c & 1;
    const float* V = isglobal ? gV : lV;
    const float* C = isglobal ? gC : lC;
    const float* W = isglobal ? gW : lW;
    float val;
    if (r < 192) {
        int rel = r >> 6, d = r & 63;
        val = 0.f;
        for (int b = 0; b < NBASES; b++)
            val += C[(layer * NREL + rel) * NBASES + b] *
                   V[((layer * NBASES + b) * DIM + d) * DIM + o];
    } else {
        int d = r - 192;
        val = W[(layer * DIM + d) * DIM + o];
    }
    wstk[idx] = val;
}

// ---------------- edge aggregation (wave per dst node) ----------------
// t[n][0:64]=t_r0, [64:128]=t_r1, [128:192]=t_r2, [192:256]=h[n] (self-loop slot)
__global__ __launch_bounds__(256) void agg_kernel(
    const float* __restrict__ h, const int* __restrict__ offs,
    const int* __restrict__ csr_se, const float* __restrict__ csr_m,
    float* __restrict__ t, int nNodes) {
    int lane = threadIdx.x & 63;
    int n = (blockIdx.x << 2) + (threadIdx.x >> 6);
    if (n >= nNodes) return;
    int beg = offs[n], end = offs[n + 1];
    float a0 = 0.f, a1 = 0.f, a2 = 0.f;
    for (int e = beg; e < end; e++) {
        int p = csr_se[e];
        float m = csr_m[e];
        float v = h[((p & 0xFFFFF) << 6) + lane];   // coalesced 256B gather
        int et = p >> 20;                            // wave-uniform
        if (et == 0)      a0 = fmaf(m, v, a0);
        else if (et == 1) a1 = fmaf(m, v, a1);
        else              a2 = fmaf(m, v, a2);
    }
    float hv = h[(n << 6) + lane];
    float* tn = t + (size_t)n * 256;
    tn[lane] = a0;
    tn[64 + lane] = a1;
    tn[128 + lane] = a2;
    tn[192 + lane] = hv;
}

// ---------------- GEMM [nRows,256] @ [256,64] + bias + activation ----------------
// act: 0 = elu, 1 = leaky_relu(0.01). Tile 128 rows/block, 256 threads.
__global__ __launch_bounds__(256) void gemm_kernel(
    const float* __restrict__ t, const float* __restrict__ W,
    const float* __restrict__ bias, float* __restrict__ hout,
    float* __restrict__ subg, int subg_off, int nRows, int act) {
    __shared__ float As[128][33];   // +1 pad: rows differ by 8 -> bank offset 8
    __shared__ float Ws[32][64];
    int tid = threadIdx.x;
    long row0 = (long)blockIdx.x * 128;
    int rgrp = (tid & 3) | ((tid >> 6) << 2);   // 0..15 -> rows rgrp*8..+7
    int c0 = ((tid >> 2) & 15) << 2;            // 4 cols
    float acc[8][4];
#pragma unroll
    for (int i = 0; i < 8; i++) {
        acc[i][0] = 0.f; acc[i][1] = 0.f; acc[i][2] = 0.f; acc[i][3] = 0.f;
    }
    for (int k0 = 0; k0 < 256; k0 += 32) {
        __syncthreads();
        // stage A chunk: 128x32
#pragma unroll
        for (int l = 0; l < 4; l++) {
            int f = l * 256 + tid;
            int r = f >> 3, kk = (f & 7) << 2;
            long gr = row0 + r;
            float4 v = make_float4(0.f, 0.f, 0.f, 0.f);
            if (gr < nRows) v = *(const float4*)&t[gr * 256 + k0 + kk];
            As[r][kk] = v.x; As[r][kk + 1] = v.y; As[r][kk + 2] = v.z; As[r][kk + 3] = v.w;
        }
        // stage W chunk: 32x64
#pragma unroll
        for (int l = 0; l < 2; l++) {
            int f = l * 256 + tid;
            int kk = f >> 4, col = (f & 15) << 2;
            *(float4*)&Ws[kk][col] = *(const float4*)&W[(k0 + kk) * 64 + col];
        }
        __syncthreads();
#pragma unroll
        for (int kk = 0; kk < 32; kk++) {
            float4 w = *(float4*)&Ws[kk][c0];
#pragma unroll
            for (int rr = 0; rr < 8; rr++) {
                float a = As[rgrp * 8 + rr][kk];
                acc[rr][0] = fmaf(a, w.x, acc[rr][0]);
                acc[rr][1] = fmaf(a, w.y, acc[rr][1]);
                acc[rr][2] = fmaf(a, w.z, acc[rr][2]);
                acc[rr][3] = fmaf(a, w.w, acc[rr][3]);
            }
        }
    }
    float4 bb = *(const float4*)&bias[c0];
#pragma unroll
    for (int rr = 0; rr < 8; rr++) {
        long row = row0 + rgrp * 8 + rr;
        if (row >= nRows) continue;
        float v[4] = {acc[rr][0] + bb.x, acc[rr][1] + bb.y,
                      acc[rr][2] + bb.z, acc[rr][3] + bb.w};
#pragma unroll
        for (int j = 0; j < 4; j++) {
            float x = v[j];
            v[j] = act ? (x > 0.f ? x : 0.01f * x)
                       : (x > 0.f ? x : expm1f(x));
        }
        float4 o = make_float4(v[0], v[1], v[2], v[3]);
        *(float4*)&hout[row * 64 + c0] = o;
        if (subg && row < BSUB)
            *(float4*)&subg[row * 192 + subg_off + c0] = o;
    }
}

// ---------------- MLP head: [4096,192] -> relu 128 -> sigmoid 1 ----------------
__global__ __launch_bounds__(256) void head_kernel(
    const float* __restrict__ subg, const float* __restrict__ w1,
    const float* __restrict__ b1, const float* __restrict__ w2,
    const float* __restrict__ b2, float* __restrict__ out) {
    __shared__ float srow[4][192];
    int lane = threadIdx.x & 63, wid = threadIdx.x >> 6;
    int row = blockIdx.x * 4 + wid;
    const float* sr = subg + (size_t)row * 192;
    srow[wid][lane] = sr[lane];
    srow[wid][64 + lane] = sr[64 + lane];
    srow[wid][128 + lane] = sr[128 + lane];
    __syncthreads();
    float acc1 = b1[lane], acc2 = b1[64 + lane];
    const float* w1a = w1 + lane * 192;
    const float* w1b = w1 + (64 + lane) * 192;
    for (int k = 0; k < 192; k++) {
        float s = srow[wid][k];
        acc1 = fmaf(s, w1a[k], acc1);
        acc2 = fmaf(s, w1b[k], acc2);
    }
    acc1 = fmaxf(acc1, 0.f);
    acc2 = fmaxf(acc2, 0.f);
    float part = acc1 * w2[lane] + acc2 * w2[64 + lane];
    for (int off = 32; off; off >>= 1) part += __shfl_down(part, off, 64);
    if (lane == 0) out[row] = 1.f / (1.f + expf(-(part + b2[0])));
}

extern "C" void kernel_launch(void* const* d_in, const int* in_sizes, int n_in,
                              void* d_out, int out_size, void* d_ws, size_t ws_size,
                              hipStream_t stream) {
    const float* x     = (const float*)d_in[0];
    const int*   src   = (const int*)d_in[1];
    const int*   dst   = (const int*)d_in[2];
    const int*   etype = (const int*)d_in[3];
    const float* mask  = (const float*)d_in[4];
    const float* mask2 = (const float*)d_in[5];
    const float* lV = (const float*)d_in[6];
    const float* lC = (const float*)d_in[7];
    const float* lW = (const float*)d_in[8];
    const float* lB = (const float*)d_in[9];
    const float* gV = (const float*)d_in[10];
    const float* gC = (const float*)d_in[11];
    const float* gW = (const float*)d_in[12];
    const float* gB = (const float*)d_in[13];
    const float* w1 = (const float*)d_in[14];
    const float* b1 = (const float*)d_in[15];
    const float* w2 = (const float*)d_in[16];
    const float* b2 = (const float*)d_in[17];
    float* out = (float*)d_out;

    // workspace carve-up (~197 MB total)
    char* ws = (char*)d_ws;
    size_t off = 0;
    auto alloc = [&](size_t bytes) {
        void* p = ws + off;
        off += (bytes + 255) & ~(size_t)255;
        return p;
    };
    float* h      = (float*)alloc((size_t)N_NODES * 64 * 4);
    float* t      = (float*)alloc((size_t)N_NODES * 256 * 4);
    int*   csr_se = (int*)alloc((size_t)N_EDGES * 4);
    float* cm1    = (float*)alloc((size_t)N_EDGES * 4);
    float* cm2    = (float*)alloc((size_t)N_EDGES * 4);
    int*   offs   = (int*)alloc((size_t)(N_NODES + 1) * 4);
    int*   cursor = (int*)alloc((size_t)N_NODES * 4);
    int*   bsum   = (int*)alloc(512 * 4);
    float* wstk   = (float*)alloc((size_t)6 * 256 * 64 * 4);
    float* subg   = (float*)alloc((size_t)BSUB * 192 * 4);

    // CSR build (cursor doubles as count buffer)
    zero_kernel<<<N_NODES / 256, 256, 0, stream>>>(cursor, N_NODES);
    hist_kernel<<<N_EDGES / 256, 256, 0, stream>>>(dst, cursor);
    scan1_kernel<<<N_NODES / 256, 256, 0, stream>>>(cursor, offs, bsum);
    scan2_kernel<<<1, 512, 0, stream>>>(bsum);
    scan3_kernel<<<N_NODES / 256, 256, 0, stream>>>(offs, bsum, cursor);
    fill_kernel<<<N_EDGES / 256, 256, 0, stream>>>(src, dst, etype, mask, mask2,
                                                   cursor, csr_se, cm1, cm2);
    wstk_kernel<<<(6 * 256 * 64) / 256, 256, 0, stream>>>(lV, lC, lW, gV, gC, gW, wstk);

    const float* hin = x;
    for (int layer = 0; layer < 3; layer++) {
        // local conv (mask, elu)
        agg_kernel<<<N_NODES / 4, 256, 0, stream>>>(hin, offs, csr_se, cm1, t, N_NODES);
        gemm_kernel<<<N_NODES / 128, 256, 0, stream>>>(
            t, wstk + (size_t)(layer * 2 + 0) * 256 * 64, lB + layer * 64,
            h, nullptr, 0, N_NODES, 0);
        hin = h;
        // global conv (mask2, leaky_relu); last layer only needs subgraph rows
        int nG = (layer == 2) ? BSUB : N_NODES;
        agg_kernel<<<(nG + 3) / 4, 256, 0, stream>>>(h, offs, csr_se, cm2, t, nG);
        gemm_kernel<<<(nG + 127) / 128, 256, 0, stream>>>(
            t, wstk + (size_t)(layer * 2 + 1) * 256 * 64, gB + layer * 64,
            h, subg, layer * 64, nG, 1);
    }
    head_kernel<<<BSUB / 4, 256, 0, stream>>>(subg, w1, b1, w2, b2, out);
}

// Round 2
// 1196.212 us; speedup vs baseline: 1.6010x; 1.6010x over previous
//
#include <hip/hip_runtime.h>
#include <math.h>

#define N_NODES 131072
#define N_EDGES 2097152
#define DIM     64
#define BSUB    4096
#define NREL    3
#define NBASES  2
#define KDIM    192   // NB*64 basis slots + 64 self-loop

// ---------------- CSR build ----------------

__global__ void zero_kernel(int* __restrict__ p, int n) {
    int i = blockIdx.x * 256 + threadIdx.x;
    if (i < n) p[i] = 0;
}

__global__ void hist_kernel(const int* __restrict__ dst, int* __restrict__ cnt) {
    int e = blockIdx.x * 256 + threadIdx.x;
    if (e < N_EDGES) atomicAdd(&cnt[dst[e]], 1);
}

// block-level exclusive scan of 256 counts; block total -> bsum
__global__ void scan1_kernel(const int* __restrict__ cnt, int* __restrict__ scanned,
                             int* __restrict__ bsum) {
    __shared__ int s[256];
    int tid = threadIdx.x;
    int i = blockIdx.x * 256 + tid;
    int v = cnt[i];
    s[tid] = v;
    __syncthreads();
    int val = v;
    for (int off = 1; off < 256; off <<= 1) {
        int tmp = (tid >= off) ? s[tid - off] : 0;
        __syncthreads();
        val += tmp;
        s[tid] = val;
        __syncthreads();
    }
    scanned[i] = val - v;                 // exclusive
    if (tid == 255) bsum[blockIdx.x] = val;  // inclusive total
}

// exclusive scan of the 512 block sums, in place
__global__ void scan2_kernel(int* __restrict__ bsum) {
    __shared__ int s[512];
    int tid = threadIdx.x;
    int v = bsum[tid];
    s[tid] = v;
    __syncthreads();
    int val = v;
    for (int off = 1; off < 512; off <<= 1) {
        int tmp = (tid >= off) ? s[tid - off] : 0;
        __syncthreads();
        val += tmp;
        s[tid] = val;
        __syncthreads();
    }
    bsum[tid] = val - v;
}

__global__ void scan3_kernel(int* __restrict__ offs, const int* __restrict__ bsum,
                             int* __restrict__ cursor) {
    int i = blockIdx.x * 256 + threadIdx.x;
    int v = offs[i] + bsum[blockIdx.x];
    offs[i] = v;
    cursor[i] = v;
    if (i == 0) offs[N_NODES] = N_EDGES;
}

// scatter edges into CSR order; pack src (17b) | etype<<20
__global__ void fill_kernel(const int* __restrict__ src, const int* __restrict__ dst,
                            const int* __restrict__ et, const float* __restrict__ m1,
                            const float* __restrict__ m2, int* __restrict__ cursor,
                            int* __restrict__ csr_se, float* __restrict__ cm1,
                            float* __restrict__ cm2) {
    int e = blockIdx.x * 256 + threadIdx.x;
    if (e >= N_EDGES) return;
    int d = dst[e];
    int p = atomicAdd(&cursor[d], 1);
    csr_se[p] = src[e] | (et[e] << 20);
    cm1[p] = m1[e];
    cm2[p] = m2[e];
}

// ---------------- weight stacking ----------------
// wstk[conv][192][64]: rows 0..63 = V_b0, 64..127 = V_b1, 128..191 = W_self
__global__ void wstk_kernel(const float* __restrict__ lV, const float* __restrict__ lW,
                            const float* __restrict__ gV, const float* __restrict__ gW,
                            float* __restrict__ wstk) {
    int idx = blockIdx.x * 256 + threadIdx.x;   // 6*192*64 total
    if (idx >= 6 * KDIM * DIM) return;
    int o = idx & 63;
    int r = (idx >> 6) % KDIM;
    int c = idx / (KDIM * DIM);   // conv 0..5
    int layer = c >> 1;
    bool isglobal = c & 1;
    const float* V = isglobal ? gV : lV;
    const float* W = isglobal ? gW : lW;
    float val;
    if (r < NBASES * DIM) {
        int b = r >> 6, d = r & 63;
        val = V[((layer * NBASES + b) * DIM + d) * DIM + o];
    } else {
        int d = r - NBASES * DIM;
        val = W[(layer * DIM + d) * DIM + o];
    }
    wstk[idx] = val;
}

// ---------------- edge aggregation (wave per dst node, basis-space) ----------------
// t[n][0:64] = u_b0, [64:128] = u_b1, [128:192] = h[n]  (K = 192)
// quarter-wave gathers: lanes q*16..q*16+15 handle edge j+q with float4 each,
// so one VMEM instruction fetches 4 edges' 256B rows.
__global__ __launch_bounds__(256) void agg_kernel(
    const float* __restrict__ h, const int* __restrict__ offs,
    const int* __restrict__ csr_se, const float* __restrict__ csr_m,
    const float* __restrict__ Cc,    // [R][NB] = 6 floats for this conv
    float* __restrict__ t, int nNodes) {
    int lane = threadIdx.x & 63;
    int n = (blockIdx.x << 2) + (threadIdx.x >> 6);
    if (n >= nNodes) return;
    int q  = lane >> 4;     // quarter 0..3
    int ql = lane & 15;     // lane within quarter
    float Ca0 = Cc[0], Cb0 = Cc[1], Ca1 = Cc[2], Cb1 = Cc[3], Ca2 = Cc[4], Cb2 = Cc[5];
    int beg = offs[n], end = offs[n + 1];
    float4 a0 = make_float4(0.f, 0.f, 0.f, 0.f);
    float4 a1 = make_float4(0.f, 0.f, 0.f, 0.f);
    for (int base = beg; base < end; base += 64) {
        int cnt = min(64, end - base);
        int p = 0; float m = 0.f;
        if (lane < cnt) { p = csr_se[base + lane]; m = csr_m[base + lane]; }
        for (int j = 0; j < cnt; j += 8) {
            int j0 = j + q, j1 = j + 4 + q;
            int i0 = j0 < cnt ? j0 : 0;
            int i1 = j1 < cnt ? j1 : 0;
            int pe0 = __shfl(p, i0, 64);
            int pe1 = __shfl(p, i1, 64);
            float me0 = __shfl(m, i0, 64);
            float me1 = __shfl(m, i1, 64);
            if (j0 >= cnt) me0 = 0.f;
            if (j1 >= cnt) me1 = 0.f;
            const float4 v0 = *(const float4*)&h[((pe0 & 0xFFFFF) << 6) + (ql << 2)];
            const float4 v1 = *(const float4*)&h[((pe1 & 0xFFFFF) << 6) + (ql << 2)];
            int et0 = pe0 >> 20, et1 = pe1 >> 20;
            float caA = et0 == 0 ? Ca0 : (et0 == 1 ? Ca1 : Ca2);
            float cbA = et0 == 0 ? Cb0 : (et0 == 1 ? Cb1 : Cb2);
            float caB = et1 == 0 ? Ca0 : (et1 == 1 ? Ca1 : Ca2);
            float cbB = et1 == 0 ? Cb0 : (et1 == 1 ? Cb1 : Cb2);
            float c0A = me0 * caA, c1A = me0 * cbA;
            float c0B = me1 * caB, c1B = me1 * cbB;
            a0.x = fmaf(c0A, v0.x, a0.x); a0.y = fmaf(c0A, v0.y, a0.y);
            a0.z = fmaf(c0A, v0.z, a0.z); a0.w = fmaf(c0A, v0.w, a0.w);
            a1.x = fmaf(c1A, v0.x, a1.x); a1.y = fmaf(c1A, v0.y, a1.y);
            a1.z = fmaf(c1A, v0.z, a1.z); a1.w = fmaf(c1A, v0.w, a1.w);
            a0.x = fmaf(c0B, v1.x, a0.x); a0.y = fmaf(c0B, v1.y, a0.y);
            a0.z = fmaf(c0B, v1.z, a0.z); a0.w = fmaf(c0B, v1.w, a0.w);
            a1.x = fmaf(c1B, v1.x, a1.x); a1.y = fmaf(c1B, v1.y, a1.y);
            a1.z = fmaf(c1B, v1.z, a1.z); a1.w = fmaf(c1B, v1.w, a1.w);
        }
    }
    // butterfly-sum the 4 quarters: lanes {ql, ql+16, ql+32, ql+48}
#pragma unroll
    for (int off = 16; off < 64; off <<= 1) {
        a0.x += __shfl_xor(a0.x, off, 64); a0.y += __shfl_xor(a0.y, off, 64);
        a0.z += __shfl_xor(a0.z, off, 64); a0.w += __shfl_xor(a0.w, off, 64);
        a1.x += __shfl_xor(a1.x, off, 64); a1.y += __shfl_xor(a1.y, off, 64);
        a1.z += __shfl_xor(a1.z, off, 64); a1.w += __shfl_xor(a1.w, off, 64);
    }
    // write t row: lanes 0-15 -> u_b0, 16-31 -> u_b1, 32-47 -> h[n]
    float4 outv;
    if (q == 0)      outv = a0;
    else if (q == 1) outv = a1;
    else             outv = *(const float4*)&h[(n << 6) + (ql << 2)];
    if (q < 3)
        *(float4*)&t[(size_t)n * KDIM + (q << 6) + (ql << 2)] = outv;
}

// ---------------- GEMM [nRows,192] @ [192,64] + bias + activation ----------------
// act: 0 = elu, 1 = leaky_relu(0.01). Tile 128 rows/block, 256 threads.
__global__ __launch_bounds__(256) void gemm_kernel(
    const float* __restrict__ t, const float* __restrict__ W,
    const float* __restrict__ bias, float* __restrict__ hout,
    float* __restrict__ subg, int subg_off, int nRows, int act) {
    __shared__ float As[128][33];
    __shared__ float Ws[32][64];
    int tid = threadIdx.x;
    long row0 = (long)blockIdx.x * 128;
    int rgrp = (tid & 3) | ((tid >> 6) << 2);   // 0..15 -> rows rgrp*8..+7
    int c0 = ((tid >> 2) & 15) << 2;            // 4 cols
    float acc[8][4];
#pragma unroll
    for (int i = 0; i < 8; i++) {
        acc[i][0] = 0.f; acc[i][1] = 0.f; acc[i][2] = 0.f; acc[i][3] = 0.f;
    }
    for (int k0 = 0; k0 < KDIM; k0 += 32) {
        __syncthreads();
        // stage A chunk: 128x32
#pragma unroll
        for (int l = 0; l < 4; l++) {
            int f = l * 256 + tid;
            int r = f >> 3, kk = (f & 7) << 2;
            long gr = row0 + r;
            float4 v = make_float4(0.f, 0.f, 0.f, 0.f);
            if (gr < nRows) v = *(const float4*)&t[gr * KDIM + k0 + kk];
            As[r][kk] = v.x; As[r][kk + 1] = v.y; As[r][kk + 2] = v.z; As[r][kk + 3] = v.w;
        }
        // stage W chunk: 32x64
#pragma unroll
        for (int l = 0; l < 2; l++) {
            int f = l * 256 + tid;
            int kk = f >> 4, col = (f & 15) << 2;
            *(float4*)&Ws[kk][col] = *(const float4*)&W[(k0 + kk) * 64 + col];
        }
        __syncthreads();
#pragma unroll
        for (int kk = 0; kk < 32; kk++) {
            float4 w = *(float4*)&Ws[kk][c0];
#pragma unroll
            for (int rr = 0; rr < 8; rr++) {
                float a = As[rgrp * 8 + rr][kk];
                acc[rr][0] = fmaf(a, w.x, acc[rr][0]);
                acc[rr][1] = fmaf(a, w.y, acc[rr][1]);
                acc[rr][2] = fmaf(a, w.z, acc[rr][2]);
                acc[rr][3] = fmaf(a, w.w, acc[rr][3]);
            }
        }
    }
    float4 bb = *(const float4*)&bias[c0];
#pragma unroll
    for (int rr = 0; rr < 8; rr++) {
        long row = row0 + rgrp * 8 + rr;
        if (row >= nRows) continue;
        float v[4] = {acc[rr][0] + bb.x, acc[rr][1] + bb.y,
                      acc[rr][2] + bb.z, acc[rr][3] + bb.w};
#pragma unroll
        for (int j = 0; j < 4; j++) {
            float x = v[j];
            v[j] = act ? (x > 0.f ? x : 0.01f * x)
                       : (x > 0.f ? x : expm1f(x));
        }
        float4 o = make_float4(v[0], v[1], v[2], v[3]);
        *(float4*)&hout[row * 64 + c0] = o;
        if (subg && row < BSUB)
            *(float4*)&subg[row * 192 + subg_off + c0] = o;
    }
}

// ---------------- MLP head: [4096,192] -> relu 128 -> sigmoid 1 ----------------
__global__ __launch_bounds__(256) void head_kernel(
    const float* __restrict__ subg, const float* __restrict__ w1,
    const float* __restrict__ b1, const float* __restrict__ w2,
    const float* __restrict__ b2, float* __restrict__ out) {
    __shared__ float srow[4][192];
    int lane = threadIdx.x & 63, wid = threadIdx.x >> 6;
    int row = blockIdx.x * 4 + wid;
    const float* sr = subg + (size_t)row * 192;
    srow[wid][lane] = sr[lane];
    srow[wid][64 + lane] = sr[64 + lane];
    srow[wid][128 + lane] = sr[128 + lane];
    __syncthreads();
    float acc1 = b1[lane], acc2 = b1[64 + lane];
    const float* w1a = w1 + lane * 192;
    const float* w1b = w1 + (64 + lane) * 192;
    for (int k = 0; k < 192; k++) {
        float s = srow[wid][k];
        acc1 = fmaf(s, w1a[k], acc1);
        acc2 = fmaf(s, w1b[k], acc2);
    }
    acc1 = fmaxf(acc1, 0.f);
    acc2 = fmaxf(acc2, 0.f);
    float part = acc1 * w2[lane] + acc2 * w2[64 + lane];
    for (int off = 32; off; off >>= 1) part += __shfl_down(part, off, 64);
    if (lane == 0) out[row] = 1.f / (1.f + expf(-(part + b2[0])));
}

extern "C" void kernel_launch(void* const* d_in, const int* in_sizes, int n_in,
                              void* d_out, int out_size, void* d_ws, size_t ws_size,
                              hipStream_t stream) {
    const float* x     = (const float*)d_in[0];
    const int*   src   = (const int*)d_in[1];
    const int*   dst   = (const int*)d_in[2];
    const int*   etype = (const int*)d_in[3];
    const float* mask  = (const float*)d_in[4];
    const float* mask2 = (const float*)d_in[5];
    const float* lV = (const float*)d_in[6];
    const float* lC = (const float*)d_in[7];
    const float* lW = (const float*)d_in[8];
    const float* lB = (const float*)d_in[9];
    const float* gV = (const float*)d_in[10];
    const float* gC = (const float*)d_in[11];
    const float* gW = (const float*)d_in[12];
    const float* gB = (const float*)d_in[13];
    const float* w1 = (const float*)d_in[14];
    const float* b1 = (const float*)d_in[15];
    const float* w2 = (const float*)d_in[16];
    const float* b2 = (const float*)d_in[17];
    float* out = (float*)d_out;

    // workspace carve-up
    char* ws = (char*)d_ws;
    size_t off = 0;
    auto alloc = [&](size_t bytes) {
        void* p = ws + off;
        off += (bytes + 255) & ~(size_t)255;
        return p;
    };
    float* h      = (float*)alloc((size_t)N_NODES * 64 * 4);
    float* t      = (float*)alloc((size_t)N_NODES * KDIM * 4);
    int*   csr_se = (int*)alloc((size_t)N_EDGES * 4);
    float* cm1    = (float*)alloc((size_t)N_EDGES * 4);
    float* cm2    = (float*)alloc((size_t)N_EDGES * 4);
    int*   offs   = (int*)alloc((size_t)(N_NODES + 1) * 4);
    int*   cursor = (int*)alloc((size_t)N_NODES * 4);
    int*   bsum   = (int*)alloc(512 * 4);
    float* wstk   = (float*)alloc((size_t)6 * KDIM * DIM * 4);
    float* subg   = (float*)alloc((size_t)BSUB * 192 * 4);

    // CSR build (cursor doubles as count buffer)
    zero_kernel<<<N_NODES / 256, 256, 0, stream>>>(cursor, N_NODES);
    hist_kernel<<<N_EDGES / 256, 256, 0, stream>>>(dst, cursor);
    scan1_kernel<<<N_NODES / 256, 256, 0, stream>>>(cursor, offs, bsum);
    scan2_kernel<<<1, 512, 0, stream>>>(bsum);
    scan3_kernel<<<N_NODES / 256, 256, 0, stream>>>(offs, bsum, cursor);
    fill_kernel<<<N_EDGES / 256, 256, 0, stream>>>(src, dst, etype, mask, mask2,
                                                   cursor, csr_se, cm1, cm2);
    wstk_kernel<<<(6 * KDIM * DIM + 255) / 256, 256, 0, stream>>>(lV, lW, gV, gW, wstk);

    const float* hin = x;
    for (int layer = 0; layer < 3; layer++) {
        // local conv (mask, elu); coefs lC[layer] = 6 floats
        agg_kernel<<<N_NODES / 4, 256, 0, stream>>>(hin, offs, csr_se, cm1,
                                                    lC + layer * NREL * NBASES, t, N_NODES);
        gemm_kernel<<<N_NODES / 128, 256, 0, stream>>>(
            t, wstk + (size_t)(layer * 2 + 0) * KDIM * DIM, lB + layer * 64,
            h, nullptr, 0, N_NODES, 0);
        hin = h;
        // global conv (mask2, leaky_relu); last layer only needs subgraph rows
        int nG = (layer == 2) ? BSUB : N_NODES;
        agg_kernel<<<(nG + 3) / 4, 256, 0, stream>>>(h, offs, csr_se, cm2,
                                                     gC + layer * NREL * NBASES, t, nG);
        gemm_kernel<<<(nG + 127) / 128, 256, 0, stream>>>(
            t, wstk + (size_t)(layer * 2 + 1) * KDIM * DIM, gB + layer * 64,
            h, subg, layer * 64, nG, 1);
    }
    head_kernel<<<BSUB / 4, 256, 0, stream>>>(subg, w1, b1, w2, b2, out);
}

// Round 3
// 1130.493 us; speedup vs baseline: 1.6940x; 1.0581x over previous
//
#include <hip/hip_runtime.h>
#include <math.h>

#define N_NODES 131072
#define N_EDGES 2097152
#define DIM     64
#define BSUB    4096
#define NREL    3
#define NBASES  2
#define KDIM    192   // NB*64 basis slots + 64 self-loop

// ---------------- CSR build ----------------

__global__ void zero_kernel(int* __restrict__ p, int n) {
    int i = blockIdx.x * 256 + threadIdx.x;
    if (i < n) p[i] = 0;
}

__global__ void hist_kernel(const int* __restrict__ dst, int* __restrict__ cnt) {
    int e = blockIdx.x * 256 + threadIdx.x;
    if (e < N_EDGES) atomicAdd(&cnt[dst[e]], 1);
}

// block-level exclusive scan of 256 counts; block total -> bsum
__global__ void scan1_kernel(const int* __restrict__ cnt, int* __restrict__ scanned,
                             int* __restrict__ bsum) {
    __shared__ int s[256];
    int tid = threadIdx.x;
    int i = blockIdx.x * 256 + tid;
    int v = cnt[i];
    s[tid] = v;
    __syncthreads();
    int val = v;
    for (int off = 1; off < 256; off <<= 1) {
        int tmp = (tid >= off) ? s[tid - off] : 0;
        __syncthreads();
        val += tmp;
        s[tid] = val;
        __syncthreads();
    }
    scanned[i] = val - v;                 // exclusive
    if (tid == 255) bsum[blockIdx.x] = val;  // inclusive total
}

// exclusive scan of the 512 block sums, in place
__global__ void scan2_kernel(int* __restrict__ bsum) {
    __shared__ int s[512];
    int tid = threadIdx.x;
    int v = bsum[tid];
    s[tid] = v;
    __syncthreads();
    int val = v;
    for (int off = 1; off < 512; off <<= 1) {
        int tmp = (tid >= off) ? s[tid - off] : 0;
        __syncthreads();
        val += tmp;
        s[tid] = val;
        __syncthreads();
    }
    bsum[tid] = val - v;
}

__global__ void scan3_kernel(int* __restrict__ offs, const int* __restrict__ bsum,
                             int* __restrict__ cursor) {
    int i = blockIdx.x * 256 + threadIdx.x;
    int v = offs[i] + bsum[blockIdx.x];
    offs[i] = v;
    cursor[i] = v;
    if (i == 0) offs[N_NODES] = N_EDGES;
}

// scatter edges into CSR order; ONE 16B store per edge:
// (src | etype<<20, m1, m2, pad) -> 1 cache-line touch instead of 3
__global__ void fill_kernel(const int* __restrict__ src, const int* __restrict__ dst,
                            const int* __restrict__ et, const float* __restrict__ m1,
                            const float* __restrict__ m2, int* __restrict__ cursor,
                            int4* __restrict__ csr) {
    int e = blockIdx.x * 256 + threadIdx.x;
    if (e >= N_EDGES) return;
    int d = dst[e];
    int p = atomicAdd(&cursor[d], 1);
    int4 v;
    v.x = src[e] | (et[e] << 20);
    v.y = __float_as_int(m1[e]);
    v.z = __float_as_int(m2[e]);
    v.w = 0;
    csr[p] = v;
}

// ---------------- weight stacking ----------------
// wstk[conv][192][64]: rows 0..63 = V_b0, 64..127 = V_b1, 128..191 = W_self
__global__ void wstk_kernel(const float* __restrict__ lV, const float* __restrict__ lW,
                            const float* __restrict__ gV, const float* __restrict__ gW,
                            float* __restrict__ wstk) {
    int idx = blockIdx.x * 256 + threadIdx.x;   // 6*192*64 total
    if (idx >= 6 * KDIM * DIM) return;
    int o = idx & 63;
    int r = (idx >> 6) % KDIM;
    int c = idx / (KDIM * DIM);   // conv 0..5
    int layer = c >> 1;
    bool isglobal = c & 1;
    const float* V = isglobal ? gV : lV;
    const float* W = isglobal ? gW : lW;
    float val;
    if (r < NBASES * DIM) {
        int b = r >> 6, d = r & 63;
        val = V[((layer * NBASES + b) * DIM + d) * DIM + o];
    } else {
        int d = r - NBASES * DIM;
        val = W[(layer * DIM + d) * DIM + o];
    }
    wstk[idx] = val;
}

// ---------------- edge aggregation (wave per dst node, basis-space) ----------------
// t[n][0:64] = u_b0, [64:128] = u_b1, [128:192] = h[n]  (K = 192)
// quarter-wave gathers: lanes q*16..q*16+15 handle edge j+q with float4 each,
// so one VMEM instruction fetches 4 edges' 256B rows.
// which: 0 -> use m1 (csr.y), 1 -> use m2 (csr.z)
__global__ __launch_bounds__(256) void agg_kernel(
    const float* __restrict__ h, const int* __restrict__ offs,
    const int4* __restrict__ csr, const float* __restrict__ Cc,
    int which, float* __restrict__ t, int nNodes) {
    int lane = threadIdx.x & 63;
    int n = (blockIdx.x << 2) + (threadIdx.x >> 6);
    if (n >= nNodes) return;
    int q  = lane >> 4;     // quarter 0..3
    int ql = lane & 15;     // lane within quarter
    float Ca0 = Cc[0], Cb0 = Cc[1], Ca1 = Cc[2], Cb1 = Cc[3], Ca2 = Cc[4], Cb2 = Cc[5];
    int beg = offs[n], end = offs[n + 1];
    float4 a0 = make_float4(0.f, 0.f, 0.f, 0.f);
    float4 a1 = make_float4(0.f, 0.f, 0.f, 0.f);
    for (int base = beg; base < end; base += 64) {
        int cnt = min(64, end - base);
        int p = 0; float m = 0.f;
        if (lane < cnt) {
            int4 meta = csr[base + lane];
            p = meta.x;
            m = __int_as_float(which ? meta.z : meta.y);
        }
        for (int j = 0; j < cnt; j += 8) {
            int j0 = j + q, j1 = j + 4 + q;
            int i0 = j0 < cnt ? j0 : 0;
            int i1 = j1 < cnt ? j1 : 0;
            int pe0 = __shfl(p, i0, 64);
            int pe1 = __shfl(p, i1, 64);
            float me0 = __shfl(m, i0, 64);
            float me1 = __shfl(m, i1, 64);
            if (j0 >= cnt) me0 = 0.f;
            if (j1 >= cnt) me1 = 0.f;
            const float4 v0 = *(const float4*)&h[((pe0 & 0xFFFFF) << 6) + (ql << 2)];
            const float4 v1 = *(const float4*)&h[((pe1 & 0xFFFFF) << 6) + (ql << 2)];
            int et0 = pe0 >> 20, et1 = pe1 >> 20;
            float caA = et0 == 0 ? Ca0 : (et0 == 1 ? Ca1 : Ca2);
            float cbA = et0 == 0 ? Cb0 : (et0 == 1 ? Cb1 : Cb2);
            float caB = et1 == 0 ? Ca0 : (et1 == 1 ? Ca1 : Ca2);
            float cbB = et1 == 0 ? Cb0 : (et1 == 1 ? Cb1 : Cb2);
            float c0A = me0 * caA, c1A = me0 * cbA;
            float c0B = me1 * caB, c1B = me1 * cbB;
            a0.x = fmaf(c0A, v0.x, a0.x); a0.y = fmaf(c0A, v0.y, a0.y);
            a0.z = fmaf(c0A, v0.z, a0.z); a0.w = fmaf(c0A, v0.w, a0.w);
            a1.x = fmaf(c1A, v0.x, a1.x); a1.y = fmaf(c1A, v0.y, a1.y);
            a1.z = fmaf(c1A, v0.z, a1.z); a1.w = fmaf(c1A, v0.w, a1.w);
            a0.x = fmaf(c0B, v1.x, a0.x); a0.y = fmaf(c0B, v1.y, a0.y);
            a0.z = fmaf(c0B, v1.z, a0.z); a0.w = fmaf(c0B, v1.w, a0.w);
            a1.x = fmaf(c1B, v1.x, a1.x); a1.y = fmaf(c1B, v1.y, a1.y);
            a1.z = fmaf(c1B, v1.z, a1.z); a1.w = fmaf(c1B, v1.w, a1.w);
        }
    }
    // butterfly-sum the 4 quarters: lanes {ql, ql+16, ql+32, ql+48}
#pragma unroll
    for (int off = 16; off < 64; off <<= 1) {
        a0.x += __shfl_xor(a0.x, off, 64); a0.y += __shfl_xor(a0.y, off, 64);
        a0.z += __shfl_xor(a0.z, off, 64); a0.w += __shfl_xor(a0.w, off, 64);
        a1.x += __shfl_xor(a1.x, off, 64); a1.y += __shfl_xor(a1.y, off, 64);
        a1.z += __shfl_xor(a1.z, off, 64); a1.w += __shfl_xor(a1.w, off, 64);
    }
    // write t row: lanes 0-15 -> u_b0, 16-31 -> u_b1, 32-47 -> h[n]
    float4 outv;
    if (q == 0)      outv = a0;
    else if (q == 1) outv = a1;
    else             outv = *(const float4*)&h[(n << 6) + (ql << 2)];
    if (q < 3)
        *(float4*)&t[(size_t)n * KDIM + (q << 6) + (ql << 2)] = outv;
}

// ---------------- GEMM [nRows,192] @ [192,64] + bias + activation ----------------
// act: 0 = elu, 1 = leaky_relu(0.01). Tile 128 rows/block, 256 threads.
__global__ __launch_bounds__(256) void gemm_kernel(
    const float* __restrict__ t, const float* __restrict__ W,
    const float* __restrict__ bias, float* __restrict__ hout,
    float* __restrict__ subg, int subg_off, int nRows, int act) {
    __shared__ float As[128][33];
    __shared__ float Ws[32][64];
    int tid = threadIdx.x;
    long row0 = (long)blockIdx.x * 128;
    int rgrp = (tid & 3) | ((tid >> 6) << 2);   // 0..15 -> rows rgrp*8..+7
    int c0 = ((tid >> 2) & 15) << 2;            // 4 cols
    float acc[8][4];
#pragma unroll
    for (int i = 0; i < 8; i++) {
        acc[i][0] = 0.f; acc[i][1] = 0.f; acc[i][2] = 0.f; acc[i][3] = 0.f;
    }
    for (int k0 = 0; k0 < KDIM; k0 += 32) {
        __syncthreads();
        // stage A chunk: 128x32
#pragma unroll
        for (int l = 0; l < 4; l++) {
            int f = l * 256 + tid;
            int r = f >> 3, kk = (f & 7) << 2;
            long gr = row0 + r;
            float4 v = make_float4(0.f, 0.f, 0.f, 0.f);
            if (gr < nRows) v = *(const float4*)&t[gr * KDIM + k0 + kk];
            As[r][kk] = v.x; As[r][kk + 1] = v.y; As[r][kk + 2] = v.z; As[r][kk + 3] = v.w;
        }
        // stage W chunk: 32x64
#pragma unroll
        for (int l = 0; l < 2; l++) {
            int f = l * 256 + tid;
            int kk = f >> 4, col = (f & 15) << 2;
            *(float4*)&Ws[kk][col] = *(const float4*)&W[(k0 + kk) * 64 + col];
        }
        __syncthreads();
#pragma unroll
        for (int kk = 0; kk < 32; kk++) {
            float4 w = *(float4*)&Ws[kk][c0];
#pragma unroll
            for (int rr = 0; rr < 8; rr++) {
                float a = As[rgrp * 8 + rr][kk];
                acc[rr][0] = fmaf(a, w.x, acc[rr][0]);
                acc[rr][1] = fmaf(a, w.y, acc[rr][1]);
                acc[rr][2] = fmaf(a, w.z, acc[rr][2]);
                acc[rr][3] = fmaf(a, w.w, acc[rr][3]);
            }
        }
    }
    float4 bb = *(const float4*)&bias[c0];
#pragma unroll
    for (int rr = 0; rr < 8; rr++) {
        long row = row0 + rgrp * 8 + rr;
        if (row >= nRows) continue;
        float v[4] = {acc[rr][0] + bb.x, acc[rr][1] + bb.y,
                      acc[rr][2] + bb.z, acc[rr][3] + bb.w};
#pragma unroll
        for (int j = 0; j < 4; j++) {
            float x = v[j];
            v[j] = act ? (x > 0.f ? x : 0.01f * x)
                       : (x > 0.f ? x : expm1f(x));
        }
        float4 o = make_float4(v[0], v[1], v[2], v[3]);
        *(float4*)&hout[row * 64 + c0] = o;
        if (subg && row < BSUB)
            *(float4*)&subg[row * 192 + subg_off + c0] = o;
    }
}

// ---------------- MLP head: [4096,192] -> relu 128 -> sigmoid 1 ----------------
__global__ __launch_bounds__(256) void head_kernel(
    const float* __restrict__ subg, const float* __restrict__ w1,
    const float* __restrict__ b1, const float* __restrict__ w2,
    const float* __restrict__ b2, float* __restrict__ out) {
    __shared__ float srow[4][192];
    int lane = threadIdx.x & 63, wid = threadIdx.x >> 6;
    int row = blockIdx.x * 4 + wid;
    const float* sr = subg + (size_t)row * 192;
    srow[wid][lane] = sr[lane];
    srow[wid][64 + lane] = sr[64 + lane];
    srow[wid][128 + lane] = sr[128 + lane];
    __syncthreads();
    float acc1 = b1[lane], acc2 = b1[64 + lane];
    const float* w1a = w1 + lane * 192;
    const float* w1b = w1 + (64 + lane) * 192;
    for (int k = 0; k < 192; k++) {
        float s = srow[wid][k];
        acc1 = fmaf(s, w1a[k], acc1);
        acc2 = fmaf(s, w1b[k], acc2);
    }
    acc1 = fmaxf(acc1, 0.f);
    acc2 = fmaxf(acc2, 0.f);
    float part = acc1 * w2[lane] + acc2 * w2[64 + lane];
    for (int off = 32; off; off >>= 1) part += __shfl_down(part, off, 64);
    if (lane == 0) out[row] = 1.f / (1.f + expf(-(part + b2[0])));
}

extern "C" void kernel_launch(void* const* d_in, const int* in_sizes, int n_in,
                              void* d_out, int out_size, void* d_ws, size_t ws_size,
                              hipStream_t stream) {
    const float* x     = (const float*)d_in[0];
    const int*   src   = (const int*)d_in[1];
    const int*   dst   = (const int*)d_in[2];
    const int*   etype = (const int*)d_in[3];
    const float* mask  = (const float*)d_in[4];
    const float* mask2 = (const float*)d_in[5];
    const float* lV = (const float*)d_in[6];
    const float* lC = (const float*)d_in[7];
    const float* lW = (const float*)d_in[8];
    const float* lB = (const float*)d_in[9];
    const float* gV = (const float*)d_in[10];
    const float* gC = (const float*)d_in[11];
    const float* gW = (const float*)d_in[12];
    const float* gB = (const float*)d_in[13];
    const float* w1 = (const float*)d_in[14];
    const float* b1 = (const float*)d_in[15];
    const float* w2 = (const float*)d_in[16];
    const float* b2 = (const float*)d_in[17];
    float* out = (float*)d_out;

    // workspace carve-up
    char* ws = (char*)d_ws;
    size_t off = 0;
    auto alloc = [&](size_t bytes) {
        void* p = ws + off;
        off += (bytes + 255) & ~(size_t)255;
        return p;
    };
    float* h      = (float*)alloc((size_t)N_NODES * 64 * 4);
    float* t      = (float*)alloc((size_t)N_NODES * KDIM * 4);
    int4*  csr    = (int4*)alloc((size_t)N_EDGES * 16);
    int*   offs   = (int*)alloc((size_t)(N_NODES + 1) * 4);
    int*   cursor = (int*)alloc((size_t)N_NODES * 4);
    int*   bsum   = (int*)alloc(512 * 4);
    float* wstk   = (float*)alloc((size_t)6 * KDIM * DIM * 4);
    float* subg   = (float*)alloc((size_t)BSUB * 192 * 4);

    // CSR build (cursor doubles as count buffer)
    zero_kernel<<<N_NODES / 256, 256, 0, stream>>>(cursor, N_NODES);
    hist_kernel<<<N_EDGES / 256, 256, 0, stream>>>(dst, cursor);
    scan1_kernel<<<N_NODES / 256, 256, 0, stream>>>(cursor, offs, bsum);
    scan2_kernel<<<1, 512, 0, stream>>>(bsum);
    scan3_kernel<<<N_NODES / 256, 256, 0, stream>>>(offs, bsum, cursor);
    fill_kernel<<<N_EDGES / 256, 256, 0, stream>>>(src, dst, etype, mask, mask2,
                                                   cursor, csr);
    wstk_kernel<<<(6 * KDIM * DIM + 255) / 256, 256, 0, stream>>>(lV, lW, gV, gW, wstk);

    const float* hin = x;
    for (int layer = 0; layer < 3; layer++) {
        // local conv (mask, elu); coefs lC[layer] = 6 floats
        agg_kernel<<<N_NODES / 4, 256, 0, stream>>>(hin, offs, csr,
                                                    lC + layer * NREL * NBASES, 0, t, N_NODES);
        gemm_kernel<<<N_NODES / 128, 256, 0, stream>>>(
            t, wstk + (size_t)(layer * 2 + 0) * KDIM * DIM, lB + layer * 64,
            h, nullptr, 0, N_NODES, 0);
        hin = h;
        // global conv (mask2, leaky_relu); last layer only needs subgraph rows
        int nG = (layer == 2) ? BSUB : N_NODES;
        agg_kernel<<<(nG + 3) / 4, 256, 0, stream>>>(h, offs, csr,
                                                     gC + layer * NREL * NBASES, 1, t, nG);
        gemm_kernel<<<(nG + 127) / 128, 256, 0, stream>>>(
            t, wstk + (size_t)(layer * 2 + 1) * KDIM * DIM, gB + layer * 64,
            h, subg, layer * 64, nG, 1);
    }
    head_kernel<<<BSUB / 4, 256, 0, stream>>>(subg, w1, b1, w2, b2, out);
}

// Round 4
// 1003.747 us; speedup vs baseline: 1.9079x; 1.1263x over previous
//
#include <hip/hip_runtime.h>
#include <math.h>

#define N_NODES 131072
#define N_EDGES 2097152
#define DIM     64
#define BSUB    4096
#define NREL    3
#define NBASES  2
#define KDIM    192   // NB*64 basis slots + 64 self-loop

typedef unsigned short u16;

__device__ __forceinline__ float bf2f(u16 x) {
    return __uint_as_float(((unsigned)x) << 16);
}
__device__ __forceinline__ u16 f2bf(float f) {
    unsigned u = __float_as_uint(f);
    unsigned r = (u + 0x7FFFu + ((u >> 16) & 1u)) >> 16;   // RNE
    return (u16)r;
}
__device__ __forceinline__ float4 bf4_to_f4(ushort4 u) {
    return make_float4(bf2f(u.x), bf2f(u.y), bf2f(u.z), bf2f(u.w));
}
__device__ __forceinline__ ushort4 f4_to_bf4(float4 v) {
    ushort4 o; o.x = f2bf(v.x); o.y = f2bf(v.y); o.z = f2bf(v.z); o.w = f2bf(v.w);
    return o;
}

// ---------------- CSR build ----------------

__global__ void zero_kernel(int* __restrict__ p, int n) {
    int i = blockIdx.x * 256 + threadIdx.x;
    if (i < n) p[i] = 0;
}

__global__ void hist_kernel(const int* __restrict__ dst, int* __restrict__ cnt) {
    int e = blockIdx.x * 256 + threadIdx.x;
    if (e < N_EDGES) atomicAdd(&cnt[dst[e]], 1);
}

__global__ void scan1_kernel(const int* __restrict__ cnt, int* __restrict__ scanned,
                             int* __restrict__ bsum) {
    __shared__ int s[256];
    int tid = threadIdx.x;
    int i = blockIdx.x * 256 + tid;
    int v = cnt[i];
    s[tid] = v;
    __syncthreads();
    int val = v;
    for (int off = 1; off < 256; off <<= 1) {
        int tmp = (tid >= off) ? s[tid - off] : 0;
        __syncthreads();
        val += tmp;
        s[tid] = val;
        __syncthreads();
    }
    scanned[i] = val - v;                 // exclusive
    if (tid == 255) bsum[blockIdx.x] = val;
}

__global__ void scan2_kernel(int* __restrict__ bsum) {
    __shared__ int s[512];
    int tid = threadIdx.x;
    int v = bsum[tid];
    s[tid] = v;
    __syncthreads();
    int val = v;
    for (int off = 1; off < 512; off <<= 1) {
        int tmp = (tid >= off) ? s[tid - off] : 0;
        __syncthreads();
        val += tmp;
        s[tid] = val;
        __syncthreads();
    }
    bsum[tid] = val - v;
}

__global__ void scan3_kernel(int* __restrict__ offs, const int* __restrict__ bsum,
                             int* __restrict__ cursor) {
    int i = blockIdx.x * 256 + threadIdx.x;
    int v = offs[i] + bsum[blockIdx.x];
    offs[i] = v;
    cursor[i] = v;
    if (i == 0) offs[N_NODES] = N_EDGES;
}

// scatter edges into CSR order; ONE 16B store per edge
__global__ void fill_kernel(const int* __restrict__ src, const int* __restrict__ dst,
                            const int* __restrict__ et, const float* __restrict__ m1,
                            const float* __restrict__ m2, int* __restrict__ cursor,
                            int4* __restrict__ csr) {
    int e = blockIdx.x * 256 + threadIdx.x;
    if (e >= N_EDGES) return;
    int d = dst[e];
    int p = atomicAdd(&cursor[d], 1);
    int4 v;
    v.x = src[e] | (et[e] << 20);
    v.y = __float_as_int(m1[e]);
    v.z = __float_as_int(m2[e]);
    v.w = 0;
    csr[p] = v;
}

// ---------------- x -> bf16 convert ----------------
__global__ void cvt_kernel(const float4* __restrict__ x, ushort4* __restrict__ hb, int n4) {
    int i = blockIdx.x * 256 + threadIdx.x;
    if (i < n4) hb[i] = f4_to_bf4(x[i]);
}

// ---------------- weight stacking ----------------
// wstk[conv][192][64]: rows 0..63 = V_b0, 64..127 = V_b1, 128..191 = W_self
__global__ void wstk_kernel(const float* __restrict__ lV, const float* __restrict__ lW,
                            const float* __restrict__ gV, const float* __restrict__ gW,
                            float* __restrict__ wstk) {
    int idx = blockIdx.x * 256 + threadIdx.x;   // 6*192*64 total
    if (idx >= 6 * KDIM * DIM) return;
    int o = idx & 63;
    int r = (idx >> 6) % KDIM;
    int c = idx / (KDIM * DIM);   // conv 0..5
    int layer = c >> 1;
    bool isglobal = c & 1;
    const float* V = isglobal ? gV : lV;
    const float* W = isglobal ? gW : lW;
    float val;
    if (r < NBASES * DIM) {
        int b = r >> 6, d = r & 63;
        val = V[((layer * NBASES + b) * DIM + d) * DIM + o];
    } else {
        int d = r - NBASES * DIM;
        val = W[(layer * DIM + d) * DIM + o];
    }
    wstk[idx] = val;
}

// ---------------- edge aggregation (wave per dst node, basis-space, bf16 h) ------
// h: bf16 [N,64] as ushort4 (16 per row). t: bf16 [n,192] as ushort4 (48 per row).
// quarter-wave gathers: lanes q*16..q*16+15 load edge j+q's full 128B row
// (ushort4 = 4 bf16 per lane), so one VMEM instruction fetches 4 edges.
// which: 0 -> use m1 (csr.y), 1 -> use m2 (csr.z)
__global__ __launch_bounds__(256) void agg_kernel(
    const ushort4* __restrict__ hb, const int* __restrict__ offs,
    const int4* __restrict__ csr, const float* __restrict__ Cc,
    int which, ushort4* __restrict__ t, int nNodes) {
    int lane = threadIdx.x & 63;
    int n = (blockIdx.x << 2) + (threadIdx.x >> 6);
    if (n >= nNodes) return;
    int q  = lane >> 4;     // quarter 0..3
    int ql = lane & 15;     // lane within quarter
    float Ca0 = Cc[0], Cb0 = Cc[1], Ca1 = Cc[2], Cb1 = Cc[3], Ca2 = Cc[4], Cb2 = Cc[5];
    int beg = offs[n], end = offs[n + 1];
    float4 a0 = make_float4(0.f, 0.f, 0.f, 0.f);
    float4 a1 = make_float4(0.f, 0.f, 0.f, 0.f);
    for (int base = beg; base < end; base += 64) {
        int cnt = min(64, end - base);
        int p = 0; float m = 0.f;
        if (lane < cnt) {
            int4 meta = csr[base + lane];
            p = meta.x;
            m = __int_as_float(which ? meta.z : meta.y);
        }
        for (int j = 0; j < cnt; j += 8) {
            int j0 = j + q, j1 = j + 4 + q;
            int i0 = j0 < cnt ? j0 : 0;
            int i1 = j1 < cnt ? j1 : 0;
            int pe0 = __shfl(p, i0, 64);
            int pe1 = __shfl(p, i1, 64);
            float me0 = __shfl(m, i0, 64);
            float me1 = __shfl(m, i1, 64);
            if (j0 >= cnt) me0 = 0.f;
            if (j1 >= cnt) me1 = 0.f;
            ushort4 r0 = hb[((pe0 & 0xFFFFF) << 4) + ql];
            ushort4 r1 = hb[((pe1 & 0xFFFFF) << 4) + ql];
            float4 v0 = bf4_to_f4(r0);
            float4 v1 = bf4_to_f4(r1);
            int et0 = pe0 >> 20, et1 = pe1 >> 20;
            float caA = et0 == 0 ? Ca0 : (et0 == 1 ? Ca1 : Ca2);
            float cbA = et0 == 0 ? Cb0 : (et0 == 1 ? Cb1 : Cb2);
            float caB = et1 == 0 ? Ca0 : (et1 == 1 ? Ca1 : Ca2);
            float cbB = et1 == 0 ? Cb0 : (et1 == 1 ? Cb1 : Cb2);
            float c0A = me0 * caA, c1A = me0 * cbA;
            float c0B = me1 * caB, c1B = me1 * cbB;
            a0.x = fmaf(c0A, v0.x, a0.x); a0.y = fmaf(c0A, v0.y, a0.y);
            a0.z = fmaf(c0A, v0.z, a0.z); a0.w = fmaf(c0A, v0.w, a0.w);
            a1.x = fmaf(c1A, v0.x, a1.x); a1.y = fmaf(c1A, v0.y, a1.y);
            a1.z = fmaf(c1A, v0.z, a1.z); a1.w = fmaf(c1A, v0.w, a1.w);
            a0.x = fmaf(c0B, v1.x, a0.x); a0.y = fmaf(c0B, v1.y, a0.y);
            a0.z = fmaf(c0B, v1.z, a0.z); a0.w = fmaf(c0B, v1.w, a0.w);
            a1.x = fmaf(c1B, v1.x, a1.x); a1.y = fmaf(c1B, v1.y, a1.y);
            a1.z = fmaf(c1B, v1.z, a1.z); a1.w = fmaf(c1B, v1.w, a1.w);
        }
    }
    // butterfly-sum the 4 quarters
#pragma unroll
    for (int off = 16; off < 64; off <<= 1) {
        a0.x += __shfl_xor(a0.x, off, 64); a0.y += __shfl_xor(a0.y, off, 64);
        a0.z += __shfl_xor(a0.z, off, 64); a0.w += __shfl_xor(a0.w, off, 64);
        a1.x += __shfl_xor(a1.x, off, 64); a1.y += __shfl_xor(a1.y, off, 64);
        a1.z += __shfl_xor(a1.z, off, 64); a1.w += __shfl_xor(a1.w, off, 64);
    }
    // write t row: lanes 0-15 -> u_b0, 16-31 -> u_b1, 32-47 -> h[n] (bf16 passthrough)
    ushort4 outv;
    if (q == 0)      outv = f4_to_bf4(a0);
    else if (q == 1) outv = f4_to_bf4(a1);
    else             outv = hb[(n << 4) + ql];
    if (q < 3)
        t[(size_t)n * 48 + (q << 4) + ql] = outv;
}

// ---------------- GEMM [nRows,192(bf16)] @ [192,64(f32)] + bias + activation -----
// act: 0 = elu, 1 = leaky_relu(0.01). Tile 128 rows/block, 256 threads.
// hout: bf16 [nRows,64]; subg (optional): fp32 [BSUB,192] slice.
__global__ __launch_bounds__(256) void gemm_kernel(
    const ushort4* __restrict__ t, const float* __restrict__ W,
    const float* __restrict__ bias, ushort4* __restrict__ hout,
    float* __restrict__ subg, int subg_off, int nRows, int act) {
    __shared__ float As[128][33];
    __shared__ float Ws[32][64];
    int tid = threadIdx.x;
    long row0 = (long)blockIdx.x * 128;
    int rgrp = (tid & 3) | ((tid >> 6) << 2);   // 0..15 -> rows rgrp*8..+7
    int c0 = ((tid >> 2) & 15) << 2;            // 4 cols
    float acc[8][4];
#pragma unroll
    for (int i = 0; i < 8; i++) {
        acc[i][0] = 0.f; acc[i][1] = 0.f; acc[i][2] = 0.f; acc[i][3] = 0.f;
    }
    for (int k0 = 0; k0 < KDIM; k0 += 32) {
        __syncthreads();
        // stage A chunk: 128 rows x 32 k (bf16 -> f32); 8 ushort4 per row-chunk
#pragma unroll
        for (int l = 0; l < 4; l++) {
            int f = l * 256 + tid;
            int r = f >> 3, kk4 = f & 7;
            long gr = row0 + r;
            float4 v = make_float4(0.f, 0.f, 0.f, 0.f);
            if (gr < nRows) v = bf4_to_f4(t[gr * 48 + (k0 >> 2) + kk4]);
            int kk = kk4 << 2;
            As[r][kk] = v.x; As[r][kk + 1] = v.y; As[r][kk + 2] = v.z; As[r][kk + 3] = v.w;
        }
        // stage W chunk: 32x64
#pragma unroll
        for (int l = 0; l < 2; l++) {
            int f = l * 256 + tid;
            int kk = f >> 4, col = (f & 15) << 2;
            *(float4*)&Ws[kk][col] = *(const float4*)&W[(k0 + kk) * 64 + col];
        }
        __syncthreads();
#pragma unroll
        for (int kk = 0; kk < 32; kk++) {
            float4 w = *(float4*)&Ws[kk][c0];
#pragma unroll
            for (int rr = 0; rr < 8; rr++) {
                float a = As[rgrp * 8 + rr][kk];
                acc[rr][0] = fmaf(a, w.x, acc[rr][0]);
                acc[rr][1] = fmaf(a, w.y, acc[rr][1]);
                acc[rr][2] = fmaf(a, w.z, acc[rr][2]);
                acc[rr][3] = fmaf(a, w.w, acc[rr][3]);
            }
        }
    }
    float4 bb = *(const float4*)&bias[c0];
#pragma unroll
    for (int rr = 0; rr < 8; rr++) {
        long row = row0 + rgrp * 8 + rr;
        if (row >= nRows) continue;
        float v[4] = {acc[rr][0] + bb.x, acc[rr][1] + bb.y,
                      acc[rr][2] + bb.z, acc[rr][3] + bb.w};
#pragma unroll
        for (int j = 0; j < 4; j++) {
            float x = v[j];
            v[j] = act ? (x > 0.f ? x : 0.01f * x)
                       : (x > 0.f ? x : expm1f(x));
        }
        float4 o = make_float4(v[0], v[1], v[2], v[3]);
        hout[row * 16 + (c0 >> 2)] = f4_to_bf4(o);
        if (subg && row < BSUB)
            *(float4*)&subg[row * 192 + subg_off + c0] = o;
    }
}

// ---------------- MLP head: [4096,192] -> relu 128 -> sigmoid 1 ----------------
__global__ __launch_bounds__(256) void head_kernel(
    const float* __restrict__ subg, const float* __restrict__ w1,
    const float* __restrict__ b1, const float* __restrict__ w2,
    const float* __restrict__ b2, float* __restrict__ out) {
    __shared__ float srow[4][192];
    int lane = threadIdx.x & 63, wid = threadIdx.x >> 6;
    int row = blockIdx.x * 4 + wid;
    const float* sr = subg + (size_t)row * 192;
    srow[wid][lane] = sr[lane];
    srow[wid][64 + lane] = sr[64 + lane];
    srow[wid][128 + lane] = sr[128 + lane];
    __syncthreads();
    float acc1 = b1[lane], acc2 = b1[64 + lane];
    const float* w1a = w1 + lane * 192;
    const float* w1b = w1 + (64 + lane) * 192;
    for (int k = 0; k < 192; k++) {
        float s = srow[wid][k];
        acc1 = fmaf(s, w1a[k], acc1);
        acc2 = fmaf(s, w1b[k], acc2);
    }
    acc1 = fmaxf(acc1, 0.f);
    acc2 = fmaxf(acc2, 0.f);
    float part = acc1 * w2[lane] + acc2 * w2[64 + lane];
    for (int off = 32; off; off >>= 1) part += __shfl_down(part, off, 64);
    if (lane == 0) out[row] = 1.f / (1.f + expf(-(part + b2[0])));
}

extern "C" void kernel_launch(void* const* d_in, const int* in_sizes, int n_in,
                              void* d_out, int out_size, void* d_ws, size_t ws_size,
                              hipStream_t stream) {
    const float* x     = (const float*)d_in[0];
    const int*   src   = (const int*)d_in[1];
    const int*   dst   = (const int*)d_in[2];
    const int*   etype = (const int*)d_in[3];
    const float* mask  = (const float*)d_in[4];
    const float* mask2 = (const float*)d_in[5];
    const float* lV = (const float*)d_in[6];
    const float* lC = (const float*)d_in[7];
    const float* lW = (const float*)d_in[8];
    const float* lB = (const float*)d_in[9];
    const float* gV = (const float*)d_in[10];
    const float* gC = (const float*)d_in[11];
    const float* gW = (const float*)d_in[12];
    const float* gB = (const float*)d_in[13];
    const float* w1 = (const float*)d_in[14];
    const float* b1 = (const float*)d_in[15];
    const float* w2 = (const float*)d_in[16];
    const float* b2 = (const float*)d_in[17];
    float* out = (float*)d_out;

    // workspace carve-up
    char* ws = (char*)d_ws;
    size_t off = 0;
    auto alloc = [&](size_t bytes) {
        void* p = ws + off;
        off += (bytes + 255) & ~(size_t)255;
        return p;
    };
    ushort4* h    = (ushort4*)alloc((size_t)N_NODES * 64 * 2);     // bf16 [N,64]
    ushort4* t    = (ushort4*)alloc((size_t)N_NODES * KDIM * 2);   // bf16 [N,192]
    int4*  csr    = (int4*)alloc((size_t)N_EDGES * 16);
    int*   offs   = (int*)alloc((size_t)(N_NODES + 1) * 4);
    int*   cursor = (int*)alloc((size_t)N_NODES * 4);
    int*   bsum   = (int*)alloc(512 * 4);
    float* wstk   = (float*)alloc((size_t)6 * KDIM * DIM * 4);
    float* subg   = (float*)alloc((size_t)BSUB * 192 * 4);

    // CSR build (cursor doubles as count buffer)
    zero_kernel<<<N_NODES / 256, 256, 0, stream>>>(cursor, N_NODES);
    hist_kernel<<<N_EDGES / 256, 256, 0, stream>>>(dst, cursor);
    scan1_kernel<<<N_NODES / 256, 256, 0, stream>>>(cursor, offs, bsum);
    scan2_kernel<<<1, 512, 0, stream>>>(bsum);
    scan3_kernel<<<N_NODES / 256, 256, 0, stream>>>(offs, bsum, cursor);
    fill_kernel<<<N_EDGES / 256, 256, 0, stream>>>(src, dst, etype, mask, mask2,
                                                   cursor, csr);
    wstk_kernel<<<(6 * KDIM * DIM + 255) / 256, 256, 0, stream>>>(lV, lW, gV, gW, wstk);
    cvt_kernel<<<(N_NODES * 64 / 4) / 256, 256, 0, stream>>>((const float4*)x, h,
                                                             N_NODES * 64 / 4);

    for (int layer = 0; layer < 3; layer++) {
        // local conv (mask, elu)
        agg_kernel<<<N_NODES / 4, 256, 0, stream>>>(h, offs, csr,
                                                    lC + layer * NREL * NBASES, 0, t, N_NODES);
        gemm_kernel<<<N_NODES / 128, 256, 0, stream>>>(
            t, wstk + (size_t)(layer * 2 + 0) * KDIM * DIM, lB + layer * 64,
            h, nullptr, 0, N_NODES, 0);
        // global conv (mask2, leaky_relu); last layer only needs subgraph rows
        int nG = (layer == 2) ? BSUB : N_NODES;
        agg_kernel<<<(nG + 3) / 4, 256, 0, stream>>>(h, offs, csr,
                                                     gC + layer * NREL * NBASES, 1, t, nG);
        gemm_kernel<<<(nG + 127) / 128, 256, 0, stream>>>(
            t, wstk + (size_t)(layer * 2 + 1) * KDIM * DIM, gB + layer * 64,
            h, subg, layer * 64, nG, 1);
    }
    head_kernel<<<BSUB / 4, 256, 0, stream>>>(subg, w1, b1, w2, b2, out);
}